// Round 2
// baseline (99.988 us; speedup 1.0000x reference)
//
#include <hip/hip_runtime.h>

#define IN_F   1024
#define OUT_F  1024
#define BATCH  32
#define KCOEF  97

typedef float f4 __attribute__((ext_vector_type(4)));
typedef f4 __attribute__((aligned(4))) f4u;   // 16B load at 4B alignment (gfx9 allows)

// Kernel A: per (b,i) compute segment id, 4 Lagrange basis values, and the
// byte offset of the 4-coeff window within one o-slice of w. 640 KB total,
// L2-resident for the main kernel.
__global__ __launch_bounds__(256)
void precompute_kernel(const float* __restrict__ x,
                       f4* __restrict__ basis,
                       int* __restrict__ offw) {
    int e = blockIdx.x * 256 + threadIdx.x;   // e = b*IN_F + i  (coalesced x read)
    int b = e >> 10, i = e & 1023;
    float xv = x[e];

    // segment id: matches ref rounding ((x+1)/2*32 == (x+1)*16 exactly)
    float s = (xv + 1.0f) * 16.0f;
    int id = (int)s;
    id = id < 0 ? 0 : (id > 31 ? 31 : id);

    // local coordinate on [-1,1] (exact pow2 scalings match the reference)
    float d  = xv - ((float)id * 0.0625f - 1.0f);
    float tt = fmaf(d, 32.0f, -1.0f);

    // Lagrange basis at Chebyshev-Lobatto nodes [-1,-0.5,0.5,1]
    float ap = tt + 1.0f, bp = tt + 0.5f, cm = tt - 0.5f, dm = tt - 1.0f;
    float uu = bp * cm, vv = ap * dm;
    f4 bs;
    bs.x = uu * dm * (-2.0f / 3.0f);
    bs.y = vv * cm * ( 4.0f / 3.0f);
    bs.z = vv * bp * (-4.0f / 3.0f);
    bs.w = uu * ap * ( 2.0f / 3.0f);

    basis[(i << 5) + b] = bs;                  // [i][b] layout -> coalesced in main
    offw [(i << 5) + b] = (i * KCOEF + id * 3) << 2;   // byte offset in o-slice
}

// Kernel B: one block per output feature o. Streams the 397 KB w-slice with
// 8-deep independent gathers; basis/off come coalesced from L2.
__global__ __launch_bounds__(256, 4)
void piecewise_main(const f4* __restrict__ basis,
                    const int* __restrict__ offw,
                    const float* __restrict__ w,
                    float* __restrict__ out) {
    const int o = blockIdx.x;
    const int t = threadIdx.x;
    const int b = t & 31;     // batch lane
    const int g = t >> 5;     // i-group 0..7

    const char* wb = (const char*)(w + (long)o * (IN_F * KCOEF));

    float acc[4] = {0.f, 0.f, 0.f, 0.f};

    for (int k0 = 0; k0 < 128; k0 += 8) {
        f4  bs[8];
        int off[8];
        #pragma unroll
        for (int u = 0; u < 8; ++u) {
            int idx = ((((k0 + u) << 3) + g) << 5) + b;   // i*32 + b
            bs[u]  = basis[idx];
            off[u] = offw[idx];
        }
        f4 wv[8];
        #pragma unroll
        for (int u = 0; u < 8; ++u)
            wv[u] = *(const f4u*)(wb + off[u]);
        #pragma unroll
        for (int u = 0; u < 8; ++u) {
            float s = acc[u & 3];
            s = fmaf(bs[u].x, wv[u].x, s);
            s = fmaf(bs[u].y, wv[u].y, s);
            s = fmaf(bs[u].z, wv[u].z, s);
            s = fmaf(bs[u].w, wv[u].w, s);
            acc[u & 3] = s;
        }
    }

    __shared__ float red[256];
    red[t] = (acc[0] + acc[1]) + (acc[2] + acc[3]);
    __syncthreads();
    if (t < 32) {
        float sum = red[t];
        #pragma unroll
        for (int gg = 1; gg < 8; ++gg) sum += red[gg * 32 + t];
        out[t * OUT_F + o] = sum;
    }
}

extern "C" void kernel_launch(void* const* d_in, const int* in_sizes, int n_in,
                              void* d_out, int out_size, void* d_ws, size_t ws_size,
                              hipStream_t stream) {
    const float* x = (const float*)d_in[0];
    const float* w = (const float*)d_in[1];
    float*       out = (float*)d_out;

    f4*  basis = (f4*)d_ws;                                  // 512 KB
    int* offw  = (int*)((char*)d_ws + BATCH * IN_F * 16);    // 128 KB

    precompute_kernel<<<(BATCH * IN_F) / 256, 256, 0, stream>>>(x, basis, offw);
    piecewise_main<<<OUT_F, 256, 0, stream>>>(basis, offw, w, out);
}

// Round 3
// 91.449 us; speedup vs baseline: 1.0934x; 1.0934x over previous
//
#include <hip/hip_runtime.h>

#define IN_F   1024
#define OUT_F  1024
#define BATCH  32
#define KCOEF  97
#define CROWS  32                    // rows staged per chunk
#define CFLOATS (CROWS * KCOEF)      // 3104 floats = 12416 B
#define NCHUNK (IN_F / CROWS)        // 32

typedef float f4 __attribute__((ext_vector_type(4)));

// Kernel A: per (b,i) -> 4 Lagrange basis values + dword offset (id*3) in row.
__global__ __launch_bounds__(256)
void precompute_kernel(const float* __restrict__ x,
                       f4* __restrict__ basis,
                       int* __restrict__ offw) {
    int e = blockIdx.x * 256 + threadIdx.x;   // e = b*IN_F + i
    int b = e >> 10, i = e & 1023;
    float xv = x[e];

    float s = (xv + 1.0f) * 16.0f;            // matches ref rounding exactly
    int id = (int)s;
    id = id < 0 ? 0 : (id > 31 ? 31 : id);

    float d  = xv - ((float)id * 0.0625f - 1.0f);
    float tt = fmaf(d, 32.0f, -1.0f);

    float ap = tt + 1.0f, bp = tt + 0.5f, cm = tt - 0.5f, dm = tt - 1.0f;
    float uu = bp * cm, vv = ap * dm;
    f4 bs;
    bs.x = uu * dm * (-2.0f / 3.0f);
    bs.y = vv * cm * ( 4.0f / 3.0f);
    bs.z = vv * bp * (-4.0f / 3.0f);
    bs.w = uu * ap * ( 2.0f / 3.0f);

    basis[(i << 5) + b] = bs;
    offw [(i << 5) + b] = id * 3;
}

// Kernel B: one block per o. w is read as a pure coalesced stream into a
// double-buffered LDS tile; the per-(b,i) 4-coeff gather happens in LDS.
__global__ __launch_bounds__(256, 4)
void piecewise_main(const f4* __restrict__ basis,
                    const int* __restrict__ offw,
                    const float* __restrict__ w,
                    float* __restrict__ out) {
    const int o = blockIdx.x;
    const int t = threadIdx.x;
    const int b = t & 31;     // batch lane
    const int g = t >> 5;     // row-group 0..7 (4 rows each per chunk)

    __shared__ float sh[2][CFLOATS];
    __shared__ float red[256];

    const float* wslice = w + (size_t)o * (IN_F * KCOEF);

    float stage[13];

    // prologue: chunk 0 -> regs -> sh[0]
    {
        const float* src = wslice;
        #pragma unroll
        for (int u = 0; u < 12; ++u) stage[u] = src[t + (u << 8)];
        if (t < 32) stage[12] = src[t + 3072];
        #pragma unroll
        for (int u = 0; u < 12; ++u) sh[0][t + (u << 8)] = stage[u];
        if (t < 32) sh[0][t + 3072] = stage[12];
    }
    __syncthreads();

    float acc0 = 0.f, acc1 = 0.f;

    for (int c = 0; c < NCHUNK; ++c) {
        const int cb = c & 1;

        // issue next chunk's global loads early (latency hides under compute)
        if (c + 1 < NCHUNK) {
            const float* src = wslice + (size_t)(c + 1) * CFLOATS;
            #pragma unroll
            for (int u = 0; u < 12; ++u) stage[u] = src[t + (u << 8)];
            if (t < 32) stage[12] = src[t + 3072];
        }

        // compute chunk c: 4 rows per group, gather 4 coeffs from LDS
        {
            const int ibase = c * CROWS + (g << 2);
            const float* rows = &sh[cb][(g << 2) * KCOEF];
            #pragma unroll
            for (int r = 0; r < 4; ++r) {
                const int idx = ((ibase + r) << 5) + b;
                f4 bs  = basis[idx];
                int j3 = offw[idx];
                const float* row = rows + r * KCOEF;
                float w0 = row[j3], w1 = row[j3 + 1], w2 = row[j3 + 2], w3 = row[j3 + 3];
                float v = fmaf(bs.x, w0, fmaf(bs.y, w1, fmaf(bs.z, w2, bs.w * w3)));
                if (r & 1) acc1 += v; else acc0 += v;
            }
        }

        // write staged chunk c+1 into the other buffer
        if (c + 1 < NCHUNK) {
            float* dst = sh[cb ^ 1];
            #pragma unroll
            for (int u = 0; u < 12; ++u) dst[t + (u << 8)] = stage[u];
            if (t < 32) dst[t + 3072] = stage[12];
        }
        __syncthreads();
    }

    // reduce 8 group-partials per (b, o)
    red[t] = acc0 + acc1;
    __syncthreads();
    if (t < 32) {
        float sum = red[t];
        #pragma unroll
        for (int gg = 1; gg < 8; ++gg) sum += red[gg * 32 + t];
        out[t * OUT_F + o] = sum;
    }
}

extern "C" void kernel_launch(void* const* d_in, const int* in_sizes, int n_in,
                              void* d_out, int out_size, void* d_ws, size_t ws_size,
                              hipStream_t stream) {
    const float* x = (const float*)d_in[0];
    const float* w = (const float*)d_in[1];
    float*       out = (float*)d_out;

    f4*  basis = (f4*)d_ws;                                  // 512 KB
    int* offw  = (int*)((char*)d_ws + BATCH * IN_F * 16);    // 128 KB

    precompute_kernel<<<(BATCH * IN_F) / 256, 256, 0, stream>>>(x, basis, offw);
    piecewise_main<<<OUT_F, 256, 0, stream>>>(basis, offw, w, out);
}